// Round 8
// baseline (502.031 us; speedup 1.0000x reference)
//
#include <hip/hip_runtime.h>

// LinkPrediction: per-edge 2-layer MLP routed by edge type (MoE-style).
// outputs: [0..N_EDGES) = scores, [N_EDGES..) = copy of rgcn_emb.
//
// R11. Model (verified 4 rounds): total = ~133us fixed + SUM(kernels).
// R6 score32=118us: VALU 29%, HBM 39% -> address-bound: 1 thread/edge makes
// every wave load touch 64 scattered 512B rows (64 line-transactions/instr).
// Fix: coalesced LDS staging. Block=256thr/128 edges (type-pure):
//   stage src rows, 32 lanes/row -> each instr = 2 FULL contiguous rows
//   (2 transactions, 32x fewer); XOR-swizzled LDS (c ^ (R&31)) conflict-free;
//   wave-uniform dim-half q=wave&1 keeps weights in SGPRs; dst phase reuses
//   the buffer; 12KB LDS reduction joins the two partial acc[24].
// 64KB LDS -> 2 blocks/CU -> cross-block stage/compute overlap.
// Copy interleaved 3:1 into the same grid (overlaps, proven free).
// A/B reg rotation (R7) REGRESSED (FETCH x2, scratch) - not used.

typedef float f4 __attribute__((ext_vector_type(4)));

constexpr int N_NODES = 200000;
constexpr int N_EDGES = 400000;
constexpr int EMB_DIM = 128;
constexpr int HID     = 24;
constexpr int N_TYPES = 8;
constexpr int BLK     = 256;

constexpr int CHUNKS  = 128;
constexpr int CH_SZ   = N_EDGES / CHUNKS;                  // 3125 exact
constexpr int MAX_PAD = N_EDGES + N_TYPES * (BLK - 1);     // 402040

constexpr int EB        = 128;                              // edges per score block
constexpr int SB2       = (N_EDGES + N_TYPES * 256 + EB - 1) / EB;  // 3142
constexpr int NGROUPS   = (SB2 + 2) / 3;                    // 1048 (3 score : 1 copy)
constexpr int NB_TOT    = NGROUPS * 4;                      // 4192

// ws int offsets
constexpr int OFF_CC     = 0;                               // [CHUNKS*8]
constexpr int OFF_COUNTS = OFF_CC + CHUNKS * N_TYPES;       // [8]
constexpr int OFF_POFF   = OFF_COUNTS + N_TYPES;            // [8]
constexpr int OFF_SORTED = OFF_POFF + N_TYPES;              // [MAX_PAD]
constexpr size_t WS_NEED = (size_t)(OFF_SORTED + MAX_PAD) * sizeof(int);

// ---------- K1: per-chunk histogram (no global atomics, no memset) ----------
__global__ __launch_bounds__(BLK) void hist_k(const int* __restrict__ etype,
                                              int* __restrict__ ws) {
    __shared__ int lc[N_TYPES];
    int b = blockIdx.x;
    if (threadIdx.x < N_TYPES) lc[threadIdx.x] = 0;
    __syncthreads();
    int e0 = b * CH_SZ;
    for (int e = e0 + (int)threadIdx.x; e < e0 + CH_SZ; e += BLK)
        atomicAdd(&lc[etype[e]], 1);
    __syncthreads();
    if (threadIdx.x < N_TYPES)
        ws[OFF_CC + b * N_TYPES + threadIdx.x] = lc[threadIdx.x];
}

// ---------- K2: deterministic scan + scatter (no global atomics) ----------
__global__ __launch_bounds__(BLK) void scatter_k(
        const int* __restrict__ etype, int* __restrict__ ws) {
    __shared__ int sbase[N_TYPES];
    __shared__ int tot[N_TYPES];
    __shared__ int mybase[N_TYPES];
    __shared__ int spoff[N_TYPES];
    __shared__ int lc[N_TYPES];
    int b = blockIdx.x;
    if (threadIdx.x < N_TYPES) {
        int t = threadIdx.x, s = 0, mb = 0;
        for (int c = 0; c < CHUNKS; ++c) {
            if (c == b) mb = s;
            s += ws[OFF_CC + c * N_TYPES + t];
        }
        tot[t] = s;
        mybase[t] = mb;
        lc[t] = 0;
    }
    __syncthreads();
    if (threadIdx.x == 0) {
        int off = 0;
        for (int t = 0; t < N_TYPES; ++t) {
            spoff[t] = off;
            off += ((tot[t] + BLK - 1) / BLK) * BLK;        // 256-pad per type
        }
    }
    __syncthreads();
    if (threadIdx.x < N_TYPES) {
        sbase[threadIdx.x] = spoff[threadIdx.x] + mybase[threadIdx.x];
        if (b == 0) {
            ws[OFF_COUNTS + threadIdx.x] = tot[threadIdx.x];
            ws[OFF_POFF + threadIdx.x]   = spoff[threadIdx.x];
        }
    }
    __syncthreads();
    int e0 = b * CH_SZ;
    int* sorted = ws + OFF_SORTED;
    for (int e = e0 + (int)threadIdx.x; e < e0 + CH_SZ; e += BLK) {
        int t = etype[e];
        int r = atomicAdd(&lc[t], 1);                       // LDS-local only
        sorted[sbase[t] + r] = e;
    }
}

// ---------- K3: LDS-staged coalesced-gather score + interleaved copy ----------
__device__ __forceinline__ void do_copy(const float* __restrict__ emb,
                                        float* __restrict__ out, int cb, int nb) {
    const f4* s4 = (const f4*)emb;
    f4* o4 = (f4*)(out + N_EDGES);
    const int n4 = N_NODES * EMB_DIM / 4;                   // 6.4M
    const int stride = nb * BLK;
    int i = cb * BLK + (int)threadIdx.x;
    for (; i + 3 * stride < n4; i += 4 * stride) {          // 4 loads in flight
        f4 a0 = s4[i];
        f4 a1 = s4[i + stride];
        f4 a2 = s4[i + 2 * stride];
        f4 a3 = s4[i + 3 * stride];
        __builtin_nontemporal_store(a0, &o4[i]);
        __builtin_nontemporal_store(a1, &o4[i + stride]);
        __builtin_nontemporal_store(a2, &o4[i + 2 * stride]);
        __builtin_nontemporal_store(a3, &o4[i + 3 * stride]);
    }
    for (; i < n4; i += stride) {
        f4 a = s4[i];
        __builtin_nontemporal_store(a, &o4[i]);
    }
}

__global__ __launch_bounds__(BLK) void score_lds_k(
        const float* __restrict__ emb,
        const int* __restrict__ srci, const int* __restrict__ dsti,
        const int* __restrict__ ws,
        const float* __restrict__ W1, const float* __restrict__ b1,
        const float* __restrict__ W2, const float* __restrict__ b2,
        float* __restrict__ out) {
    __shared__ float lds[EB * EMB_DIM];                     // 64 KB
    // grid interleave: every 4th block is a copy block (overlap with score)
    int b = blockIdx.x;
    int g = b >> 2, r = b & 3;
    if (r == 3) {
        do_copy(emb, out, g, NGROUPS);
        return;
    }
    int sb = g * 3 + r;                                     // score block id
    if (sb >= SB2) return;

    int poff[N_TYPES], counts[N_TYPES];
#pragma unroll
    for (int t = 0; t < N_TYPES; ++t) {
        counts[t] = ws[OFF_COUNTS + t];
        poff[t]   = ws[OFF_POFF + t];
    }
    int off = poff[N_TYPES - 1] + ((counts[N_TYPES - 1] + BLK - 1) / BLK) * BLK;
    int slot0 = sb * EB;
    if (slot0 >= off) return;
    int t = 0;
#pragma unroll
    for (int i = 1; i < N_TYPES; ++i)
        if (slot0 >= poff[i]) t = i;
    t = __builtin_amdgcn_readfirstlane(t);                  // block-uniform
    const int tbase = poff[t], cnt = counts[t];
    const int* sorted = ws + OFF_SORTED;

    const int tid  = (int)threadIdx.x;
    const int lane = tid & 63;
    const int w    = tid >> 6;                              // wave 0..3
    const int q    = __builtin_amdgcn_readfirstlane(w & 1); // dim-half (SGPR)
    const int ep   = w >> 1;                                // edge-pair half

    const int myR    = ep * 64 + lane;                      // my edge row 0..127
    const int myslot = slot0 + myR;
    const bool myvalid = (myslot - tbase) < cnt;
    const int mye = myvalid ? sorted[myslot] : 0;

    float acc[HID];
#pragma unroll
    for (int j = 0; j < HID; ++j) acc[j] = q ? 0.f : b1[t * HID + j];
    const float* W1t = W1 + (size_t)t * (2 * EMB_DIM * HID);

    const int c_st   = lane & 31;                           // stage: 16B chunk in row
    const int sub    = lane >> 5;                           // stage: row parity
    const int wrow0  = w * 32;                              // stage: rows w*32..+31

#pragma unroll 1
    for (int phase = 0; phase < 2; ++phase) {
        const int* __restrict__ nodes = phase ? dsti : srci;
        __syncthreads();                                    // buffer safe to overwrite
        // ---- stage: 32 lanes per row -> 2 full contiguous 512B rows / instr ----
        int nd[16];
#pragma unroll
        for (int k = 0; k < 16; ++k) {
            int R  = wrow0 + 2 * k + sub;
            int sl = slot0 + R;
            bool v = (sl - tbase) < cnt;
            int e2 = v ? sorted[sl] : 0;
            nd[k]  = v ? nodes[e2] : 0;
        }
#pragma unroll
        for (int k = 0; k < 16; ++k) {
            int R = wrow0 + 2 * k + sub;
            f4 val = ((const f4*)(emb + (size_t)nd[k] * EMB_DIM))[c_st];
            int gx = c_st ^ (R & 31);                       // XOR swizzle
            ((f4*)lds)[R * 32 + gx] = val;
        }
        __syncthreads();
        // ---- compute: my row, dims q*64..q*64+63, weights in SGPRs ----
        const float* wp0 = W1t + (phase * EMB_DIM + q * 64) * HID;
#pragma unroll 4
        for (int k = 0; k < 16; ++k) {
            int c  = q * 16 + k;
            int gx = c ^ (myR & 31);
            f4 rv = ((const f4*)lds)[myR * 32 + gx];
            const float* wp = wp0 + (k * 4) * HID;
#pragma unroll
            for (int j = 0; j < HID; ++j) acc[j] = fmaf(rv[0], wp[0 * HID + j], acc[j]);
#pragma unroll
            for (int j = 0; j < HID; ++j) acc[j] = fmaf(rv[1], wp[1 * HID + j], acc[j]);
#pragma unroll
            for (int j = 0; j < HID; ++j) acc[j] = fmaf(rv[2], wp[2 * HID + j], acc[j]);
#pragma unroll
            for (int j = 0; j < HID; ++j) acc[j] = fmaf(rv[3], wp[3 * HID + j], acc[j]);
        }
    }

    // ---- join the two dim-halves (q=1 -> q=0) via LDS ----
    __syncthreads();
    if (q == 1) {
#pragma unroll
        for (int j = 0; j < HID; ++j) lds[myR * HID + j] = acc[j];
    }
    __syncthreads();
    if (q == 0 && myvalid) {
        float sc = b2[t];
#pragma unroll
        for (int j = 0; j < HID; ++j) {
            float h = acc[j] + lds[myR * HID + j];
            h = (h > 0.f) ? h : 0.01f * h;                  // LeakyReLU(0.01)
            sc = fmaf(h, W2[t * HID + j], sc);
        }
        out[mye] = sc;
    }
}

// ---------- ws-too-small fallback: correctness only ----------
__device__ __forceinline__ void cc32(const f4* __restrict__ r,
                                     const float* __restrict__ w,
                                     float acc[HID]) {
#pragma unroll
    for (int k = 0; k < 8; ++k) {
        const float* wp = w + (k * 4) * HID;
#pragma unroll
        for (int j = 0; j < HID; ++j) acc[j] = fmaf(r[k][0], wp[0 * HID + j], acc[j]);
#pragma unroll
        for (int j = 0; j < HID; ++j) acc[j] = fmaf(r[k][1], wp[1 * HID + j], acc[j]);
#pragma unroll
        for (int j = 0; j < HID; ++j) acc[j] = fmaf(r[k][2], wp[2 * HID + j], acc[j]);
#pragma unroll
        for (int j = 0; j < HID; ++j) acc[j] = fmaf(r[k][3], wp[3 * HID + j], acc[j]);
    }
}

__global__ __launch_bounds__(BLK) void fallback_k(
        const float* __restrict__ emb,
        const int* __restrict__ srci, const int* __restrict__ dsti,
        const int* __restrict__ etype,
        const float* __restrict__ W1, const float* __restrict__ b1,
        const float* __restrict__ W2, const float* __restrict__ b2,
        float* __restrict__ out) {
    long long i0 = (long long)blockIdx.x * BLK + threadIdx.x;
    const f4* s4 = (const f4*)emb;
    f4* o4 = (f4*)(out + N_EDGES);
    const long long n4 = (long long)N_NODES * EMB_DIM / 4;
    for (long long i = i0; i < n4; i += (long long)gridDim.x * BLK)
        o4[i] = s4[i];
    for (int e = (int)i0; e < N_EDGES; e += gridDim.x * BLK) {
        int t = etype[e];
        int s = srci[e], d = dsti[e];
        float acc[HID];
#pragma unroll
        for (int j = 0; j < HID; ++j) acc[j] = b1[t * HID + j];
        const float* w = W1 + (size_t)t * 2 * EMB_DIM * HID;
        const f4* x0 = (const f4*)(emb + (size_t)s * EMB_DIM);
        const f4* x1 = (const f4*)(emb + (size_t)d * EMB_DIM);
        f4 A[8];
#pragma unroll 1
        for (int c = 0; c < 8; ++c) {
            const f4* xp = (c < 4) ? x0 : x1;
#pragma unroll
            for (int k = 0; k < 8; ++k) A[k] = xp[(c & 3) * 8 + k];
            cc32(A, w + c * 32 * HID, acc);
        }
        float sc = b2[t];
#pragma unroll
        for (int j = 0; j < HID; ++j) {
            float h = acc[j];
            h = (h > 0.f) ? h : 0.01f * h;
            sc = fmaf(h, W2[t * HID + j], sc);
        }
        out[e] = sc;
    }
}

extern "C" void kernel_launch(void* const* d_in, const int* in_sizes, int n_in,
                              void* d_out, int out_size, void* d_ws, size_t ws_size,
                              hipStream_t stream) {
    const float* emb   = (const float*)d_in[0];
    const int*   eidx  = (const int*)d_in[1];
    const int*   etype = (const int*)d_in[2];
    const float* W1    = (const float*)d_in[3];
    const float* b1    = (const float*)d_in[4];
    const float* W2    = (const float*)d_in[5];
    const float* b2    = (const float*)d_in[6];
    float* out = (float*)d_out;
    const int* srci = eidx;
    const int* dsti = eidx + N_EDGES;

    if (ws_size >= WS_NEED) {
        int* ws = (int*)d_ws;
        hist_k<<<CHUNKS, BLK, 0, stream>>>(etype, ws);
        scatter_k<<<CHUNKS, BLK, 0, stream>>>(etype, ws);
        score_lds_k<<<NB_TOT, BLK, 0, stream>>>(
            emb, srci, dsti, ws, W1, b1, W2, b2, out);
    } else {
        fallback_k<<<2048, BLK, 0, stream>>>(emb, srci, dsti, etype, W1, b1, W2, b2, out);
    }
}

// Round 9
// 340.807 us; speedup vs baseline: 1.4731x; 1.4731x over previous
//
#include <hip/hip_runtime.h>

// LinkPrediction: per-edge 2-layer MLP routed by edge type (MoE-style).
// outputs: [0..N_EDGES) = scores, [N_EDGES..) = copy of rgcn_emb.
//
// R12. Model (5x verified): total = ~133us fixed + SUM(kernels).
// R6 (best, 264us): score32 118 + hist/scatter 13. R7's A/B rotation
// regressed ONLY because hipcc chose VGPR=40 and spilled A[8]+B[8] to
// scratch (FETCH 251->472MB = +220MB scratch RW). R8's LDS staging: 17%
// occupancy + 450K bank conflicts. Fix R7 properly:
//   score32_k = R6 + A/B chunk rotation + __launch_bounds__(256,4)
//   -> VGPR ceiling 128 (no spill), 4 blk/CU = 16 waves/CU (~R6 occ).
//   Two independent load chains; chunk k+2 in flight under chunk k's FMAs.
//  K1 hist_k / K2 scatter_k: unchanged (proven 13us).
//  Copy fused on trailing blocks (proven free), NT stores.

typedef float f4 __attribute__((ext_vector_type(4)));

constexpr int N_NODES = 200000;
constexpr int N_EDGES = 400000;
constexpr int EMB_DIM = 128;
constexpr int HID     = 24;
constexpr int N_TYPES = 8;
constexpr int BLK     = 256;

constexpr int CHUNKS  = 128;
constexpr int CH_SZ   = N_EDGES / CHUNKS;                  // 3125 exact
constexpr int MAX_PAD = N_EDGES + N_TYPES * (BLK - 1);     // 402040
constexpr int SCORE_BLOCKS = (MAX_PAD + BLK - 1) / BLK;    // 1571
constexpr int COPY_BLOCKS  = 1024;

// ws int offsets
constexpr int OFF_CC     = 0;                               // [CHUNKS*8]
constexpr int OFF_COUNTS = OFF_CC + CHUNKS * N_TYPES;       // [8]
constexpr int OFF_POFF   = OFF_COUNTS + N_TYPES;            // [8]
constexpr int OFF_SORTED = OFF_POFF + N_TYPES;              // [MAX_PAD]
constexpr size_t WS_NEED = (size_t)(OFF_SORTED + MAX_PAD) * sizeof(int);

// ---------- K1: per-chunk histogram (no global atomics, no memset) ----------
__global__ __launch_bounds__(BLK) void hist_k(const int* __restrict__ etype,
                                              int* __restrict__ ws) {
    __shared__ int lc[N_TYPES];
    int b = blockIdx.x;
    if (threadIdx.x < N_TYPES) lc[threadIdx.x] = 0;
    __syncthreads();
    int e0 = b * CH_SZ;
    for (int e = e0 + (int)threadIdx.x; e < e0 + CH_SZ; e += BLK)
        atomicAdd(&lc[etype[e]], 1);
    __syncthreads();
    if (threadIdx.x < N_TYPES)
        ws[OFF_CC + b * N_TYPES + threadIdx.x] = lc[threadIdx.x];
}

// ---------- K2: deterministic scan + scatter (no global atomics) ----------
__global__ __launch_bounds__(BLK) void scatter_k(
        const int* __restrict__ etype, int* __restrict__ ws) {
    __shared__ int sbase[N_TYPES];
    __shared__ int tot[N_TYPES];
    __shared__ int mybase[N_TYPES];
    __shared__ int spoff[N_TYPES];
    __shared__ int lc[N_TYPES];
    int b = blockIdx.x;
    if (threadIdx.x < N_TYPES) {
        int t = threadIdx.x, s = 0, mb = 0;
        for (int c = 0; c < CHUNKS; ++c) {
            if (c == b) mb = s;
            s += ws[OFF_CC + c * N_TYPES + t];
        }
        tot[t] = s;
        mybase[t] = mb;
        lc[t] = 0;
    }
    __syncthreads();
    if (threadIdx.x == 0) {
        int off = 0;
        for (int t = 0; t < N_TYPES; ++t) {
            spoff[t] = off;
            off += ((tot[t] + BLK - 1) / BLK) * BLK;        // 256-pad per type
        }
    }
    __syncthreads();
    if (threadIdx.x < N_TYPES) {
        sbase[threadIdx.x] = spoff[threadIdx.x] + mybase[threadIdx.x];
        if (b == 0) {
            ws[OFF_COUNTS + threadIdx.x] = tot[threadIdx.x];
            ws[OFF_POFF + threadIdx.x]   = spoff[threadIdx.x];
        }
    }
    __syncthreads();
    int e0 = b * CH_SZ;
    int* sorted = ws + OFF_SORTED;
    for (int e = e0 + (int)threadIdx.x; e < e0 + CH_SZ; e += BLK) {
        int t = etype[e];
        int r = atomicAdd(&lc[t], 1);                       // LDS-local only
        sorted[sbase[t] + r] = e;
    }
}

// ---------- K3: sorted fp32 score, A/B-pipelined (no spill) + fused copy ----------
__device__ __forceinline__ void do_copy(const float* __restrict__ emb,
                                        float* __restrict__ out, int cb, int nb) {
    const f4* s4 = (const f4*)emb;
    f4* o4 = (f4*)(out + N_EDGES);
    const int n4 = N_NODES * EMB_DIM / 4;                   // 6.4M
    for (int i = cb * BLK + (int)threadIdx.x; i < n4; i += nb * BLK) {
        f4 a = s4[i];                                       // normal: warms LLC
        __builtin_nontemporal_store(a, &o4[i]);             // never re-read
    }
}

// one 128B chunk (8 x f4 = 32 k-values) against 32xHID weight strip
__device__ __forceinline__ void cc32(const f4* __restrict__ r,
                                     const float* __restrict__ w,
                                     float acc[HID]) {
#pragma unroll
    for (int k = 0; k < 8; ++k) {
        const float* wp = w + (k * 4) * HID;
#pragma unroll
        for (int j = 0; j < HID; ++j) acc[j] = fmaf(r[k][0], wp[0 * HID + j], acc[j]);
#pragma unroll
        for (int j = 0; j < HID; ++j) acc[j] = fmaf(r[k][1], wp[1 * HID + j], acc[j]);
#pragma unroll
        for (int j = 0; j < HID; ++j) acc[j] = fmaf(r[k][2], wp[2 * HID + j], acc[j]);
#pragma unroll
        for (int j = 0; j < HID; ++j) acc[j] = fmaf(r[k][3], wp[3 * HID + j], acc[j]);
    }
}

__global__ __launch_bounds__(BLK, 4) void score32_k(
        const float* __restrict__ emb,
        const int* __restrict__ srci, const int* __restrict__ dsti,
        const int* __restrict__ ws,
        const float* __restrict__ W1, const float* __restrict__ b1,
        const float* __restrict__ W2, const float* __restrict__ b2,
        float* __restrict__ out) {
    int b = blockIdx.x;
    if (b >= SCORE_BLOCKS) {
        do_copy(emb, out, b - SCORE_BLOCKS, (int)gridDim.x - SCORE_BLOCKS);
        return;
    }
    int poff[N_TYPES], counts[N_TYPES];
#pragma unroll
    for (int t = 0; t < N_TYPES; ++t) {
        counts[t] = ws[OFF_COUNTS + t];
        poff[t]   = ws[OFF_POFF + t];
    }
    int off = poff[N_TYPES - 1] + ((counts[N_TYPES - 1] + BLK - 1) / BLK) * BLK;
    int slot0 = b * BLK;
    if (slot0 >= off) return;
    int t = 0;
#pragma unroll
    for (int i = 1; i < N_TYPES; ++i)
        if (slot0 >= poff[i]) t = i;
    t = __builtin_amdgcn_readfirstlane(t);   // wave-uniform type -> scalar W loads
    int cnt = counts[t];
    int local = slot0 - poff[t] + (int)threadIdx.x;
    if (local >= cnt) return;
    const int* sorted = ws + OFF_SORTED;
    int e = sorted[slot0 + threadIdx.x];
    int s = srci[e], d = dsti[e];

    float acc[HID];
#pragma unroll
    for (int j = 0; j < HID; ++j) acc[j] = b1[t * HID + j];
    // W1[t]: rows 0..127 = src half, 128..255 = dst half (contiguous) ->
    // chunk k in [0,8): weights at W1t + k*32*HID, data from x0/x1.
    const float* W1t = W1 + (size_t)t * (2 * EMB_DIM * HID);
    const f4* x0 = (const f4*)(emb + (size_t)s * EMB_DIM);  // 32 f4
    const f4* x1 = (const f4*)(emb + (size_t)d * EMB_DIM);

    f4 A[8], B[8];
#pragma unroll
    for (int k = 0; k < 8; ++k) A[k] = x0[k];
#pragma unroll
    for (int k = 0; k < 8; ++k) B[k] = x0[8 + k];
    cc32(A, W1t + 0 * 32 * HID, acc);
#pragma unroll
    for (int k = 0; k < 8; ++k) A[k] = x0[16 + k];
    cc32(B, W1t + 1 * 32 * HID, acc);
#pragma unroll
    for (int k = 0; k < 8; ++k) B[k] = x0[24 + k];
    cc32(A, W1t + 2 * 32 * HID, acc);
#pragma unroll
    for (int k = 0; k < 8; ++k) A[k] = x1[k];
    cc32(B, W1t + 3 * 32 * HID, acc);
#pragma unroll
    for (int k = 0; k < 8; ++k) B[k] = x1[8 + k];
    cc32(A, W1t + 4 * 32 * HID, acc);
#pragma unroll
    for (int k = 0; k < 8; ++k) A[k] = x1[16 + k];
    cc32(B, W1t + 5 * 32 * HID, acc);
#pragma unroll
    for (int k = 0; k < 8; ++k) B[k] = x1[24 + k];
    cc32(A, W1t + 6 * 32 * HID, acc);
    cc32(B, W1t + 7 * 32 * HID, acc);

    float sc = b2[t];
#pragma unroll
    for (int j = 0; j < HID; ++j) {
        float h = acc[j];
        h = (h > 0.f) ? h : 0.01f * h;       // LeakyReLU(0.01)
        sc = fmaf(h, W2[t * HID + j], sc);
    }
    out[e] = sc;
}

// ---------- ws-too-small fallback: correctness only ----------
__global__ __launch_bounds__(BLK) void fallback_k(
        const float* __restrict__ emb,
        const int* __restrict__ srci, const int* __restrict__ dsti,
        const int* __restrict__ etype,
        const float* __restrict__ W1, const float* __restrict__ b1,
        const float* __restrict__ W2, const float* __restrict__ b2,
        float* __restrict__ out) {
    long long i0 = (long long)blockIdx.x * BLK + threadIdx.x;
    const f4* s4 = (const f4*)emb;
    f4* o4 = (f4*)(out + N_EDGES);
    const long long n4 = (long long)N_NODES * EMB_DIM / 4;
    for (long long i = i0; i < n4; i += (long long)gridDim.x * BLK)
        o4[i] = s4[i];
    for (int e = (int)i0; e < N_EDGES; e += gridDim.x * BLK) {
        int t = etype[e];
        int s = srci[e], d = dsti[e];
        float acc[HID];
#pragma unroll
        for (int j = 0; j < HID; ++j) acc[j] = b1[t * HID + j];
        const float* w = W1 + (size_t)t * 2 * EMB_DIM * HID;
        const f4* x0 = (const f4*)(emb + (size_t)s * EMB_DIM);
        const f4* x1 = (const f4*)(emb + (size_t)d * EMB_DIM);
        f4 A[8];
#pragma unroll 1
        for (int c = 0; c < 8; ++c) {
            const f4* xp = (c < 4) ? x0 : x1;
#pragma unroll
            for (int k = 0; k < 8; ++k) A[k] = xp[(c & 3) * 8 + k];
            cc32(A, w + c * 32 * HID, acc);
        }
        float sc = b2[t];
#pragma unroll
        for (int j = 0; j < HID; ++j) {
            float h = acc[j];
            h = (h > 0.f) ? h : 0.01f * h;
            sc = fmaf(h, W2[t * HID + j], sc);
        }
        out[e] = sc;
    }
}

extern "C" void kernel_launch(void* const* d_in, const int* in_sizes, int n_in,
                              void* d_out, int out_size, void* d_ws, size_t ws_size,
                              hipStream_t stream) {
    const float* emb   = (const float*)d_in[0];
    const int*   eidx  = (const int*)d_in[1];
    const int*   etype = (const int*)d_in[2];
    const float* W1    = (const float*)d_in[3];
    const float* b1    = (const float*)d_in[4];
    const float* W2    = (const float*)d_in[5];
    const float* b2    = (const float*)d_in[6];
    float* out = (float*)d_out;
    const int* srci = eidx;
    const int* dsti = eidx + N_EDGES;

    if (ws_size >= WS_NEED) {
        int* ws = (int*)d_ws;
        hist_k<<<CHUNKS, BLK, 0, stream>>>(etype, ws);
        scatter_k<<<CHUNKS, BLK, 0, stream>>>(etype, ws);
        score32_k<<<SCORE_BLOCKS + COPY_BLOCKS, BLK, 0, stream>>>(
            emb, srci, dsti, ws, W1, b1, W2, b2, out);
    } else {
        fallback_k<<<2048, BLK, 0, stream>>>(emb, srci, dsti, etype, W1, b1, W2, b2, out);
    }
}

// Round 11
// 260.509 us; speedup vs baseline: 1.9271x; 1.3082x over previous
//
#include <hip/hip_runtime.h>

// LinkPrediction: per-edge 2-layer MLP routed by edge type (MoE-style).
// outputs: [0..N_EDGES) = scores, [N_EDGES..) = copy of rgcn_emb.
//
// R14 = R13 + crash fix. R13 aborted: invalid-lane clamp read sorted[slot0],
// which is UNINITIALIZED when a whole 128-edge block sits in type padding ->
// garbage edge -> OOB emb read. Fix: clamp to sorted[tbase] (first edge of
// this block's type, always valid for non-empty regions).
// Design (unchanged): 2 threads/edge (src-half | dst-half): per-thread
// dependent chain halves (4 rounds of {load 128B -> 768 FMA}), waves x2
// (12500) for latency hiding, half is wave-uniform -> W1 base scalar;
// partials joined via stride-25 LDS. hist/scatter proven (13us); copy
// trailing blocks (proven free).

typedef float f4 __attribute__((ext_vector_type(4)));

constexpr int N_NODES = 200000;
constexpr int N_EDGES = 400000;
constexpr int EMB_DIM = 128;
constexpr int HID     = 24;
constexpr int N_TYPES = 8;
constexpr int BLK     = 256;

constexpr int CHUNKS  = 128;
constexpr int CH_SZ   = N_EDGES / CHUNKS;                  // 3125 exact
constexpr int MAX_PAD = N_EDGES + N_TYPES * (BLK - 1);     // 402040
constexpr int EPB     = 128;                               // edges per block
constexpr int SCORE_BLOCKS = (MAX_PAD + EPB - 1) / EPB;    // 3142
constexpr int COPY_BLOCKS  = 1024;

// ws int offsets
constexpr int OFF_CC     = 0;                               // [CHUNKS*8]
constexpr int OFF_COUNTS = OFF_CC + CHUNKS * N_TYPES;       // [8]
constexpr int OFF_POFF   = OFF_COUNTS + N_TYPES;            // [8]
constexpr int OFF_SORTED = OFF_POFF + N_TYPES;              // [MAX_PAD]
constexpr size_t WS_NEED = (size_t)(OFF_SORTED + MAX_PAD) * sizeof(int);

// ---------- K1: per-chunk histogram (no global atomics, no memset) ----------
__global__ __launch_bounds__(BLK) void hist_k(const int* __restrict__ etype,
                                              int* __restrict__ ws) {
    __shared__ int lc[N_TYPES];
    int b = blockIdx.x;
    if (threadIdx.x < N_TYPES) lc[threadIdx.x] = 0;
    __syncthreads();
    int e0 = b * CH_SZ;
    for (int e = e0 + (int)threadIdx.x; e < e0 + CH_SZ; e += BLK)
        atomicAdd(&lc[etype[e]], 1);
    __syncthreads();
    if (threadIdx.x < N_TYPES)
        ws[OFF_CC + b * N_TYPES + threadIdx.x] = lc[threadIdx.x];
}

// ---------- K2: deterministic scan + scatter (no global atomics) ----------
__global__ __launch_bounds__(BLK) void scatter_k(
        const int* __restrict__ etype, int* __restrict__ ws) {
    __shared__ int sbase[N_TYPES];
    __shared__ int tot[N_TYPES];
    __shared__ int mybase[N_TYPES];
    __shared__ int spoff[N_TYPES];
    __shared__ int lc[N_TYPES];
    int b = blockIdx.x;
    if (threadIdx.x < N_TYPES) {
        int t = threadIdx.x, s = 0, mb = 0;
        for (int c = 0; c < CHUNKS; ++c) {
            if (c == b) mb = s;
            s += ws[OFF_CC + c * N_TYPES + t];
        }
        tot[t] = s;
        mybase[t] = mb;
        lc[t] = 0;
    }
    __syncthreads();
    if (threadIdx.x == 0) {
        int off = 0;
        for (int t = 0; t < N_TYPES; ++t) {
            spoff[t] = off;
            off += ((tot[t] + BLK - 1) / BLK) * BLK;        // 256-pad per type
        }
    }
    __syncthreads();
    if (threadIdx.x < N_TYPES) {
        sbase[threadIdx.x] = spoff[threadIdx.x] + mybase[threadIdx.x];
        if (b == 0) {
            ws[OFF_COUNTS + threadIdx.x] = tot[threadIdx.x];
            ws[OFF_POFF + threadIdx.x]   = spoff[threadIdx.x];
        }
    }
    __syncthreads();
    int e0 = b * CH_SZ;
    int* sorted = ws + OFF_SORTED;
    for (int e = e0 + (int)threadIdx.x; e < e0 + CH_SZ; e += BLK) {
        int t = etype[e];
        int r = atomicAdd(&lc[t], 1);                       // LDS-local only
        sorted[sbase[t] + r] = e;
    }
}

// ---------- K3: 2-threads-per-edge fp32 score + fused copy ----------
__device__ __forceinline__ void do_copy(const float* __restrict__ emb,
                                        float* __restrict__ out, int cb, int nb) {
    const f4* s4 = (const f4*)emb;
    f4* o4 = (f4*)(out + N_EDGES);
    const int n4 = N_NODES * EMB_DIM / 4;                   // 6.4M
    for (int i = cb * BLK + (int)threadIdx.x; i < n4; i += nb * BLK) {
        f4 a = s4[i];                                       // normal: warms LLC
        __builtin_nontemporal_store(a, &o4[i]);             // never re-read
    }
}

// one 128B chunk (8 x f4 = 32 k-values) against 32xHID weight strip
__device__ __forceinline__ void cc32(const f4* __restrict__ r,
                                     const float* __restrict__ w,
                                     float acc[HID]) {
#pragma unroll
    for (int k = 0; k < 8; ++k) {
        const float* wp = w + (k * 4) * HID;
#pragma unroll
        for (int j = 0; j < HID; ++j) acc[j] = fmaf(r[k][0], wp[0 * HID + j], acc[j]);
#pragma unroll
        for (int j = 0; j < HID; ++j) acc[j] = fmaf(r[k][1], wp[1 * HID + j], acc[j]);
#pragma unroll
        for (int j = 0; j < HID; ++j) acc[j] = fmaf(r[k][2], wp[2 * HID + j], acc[j]);
#pragma unroll
        for (int j = 0; j < HID; ++j) acc[j] = fmaf(r[k][3], wp[3 * HID + j], acc[j]);
    }
}

__global__ __launch_bounds__(BLK) void score_split_k(
        const float* __restrict__ emb,
        const int* __restrict__ srci, const int* __restrict__ dsti,
        const int* __restrict__ ws,
        const float* __restrict__ W1, const float* __restrict__ b1,
        const float* __restrict__ W2, const float* __restrict__ b2,
        float* __restrict__ out) {
    __shared__ float jbuf[EPB][HID + 1];                    // stride 25: conflict-free
    int b = blockIdx.x;
    if (b >= SCORE_BLOCKS) {
        do_copy(emb, out, b - SCORE_BLOCKS, (int)gridDim.x - SCORE_BLOCKS);
        return;
    }
    int poff[N_TYPES], counts[N_TYPES];
#pragma unroll
    for (int t = 0; t < N_TYPES; ++t) {
        counts[t] = ws[OFF_COUNTS + t];
        poff[t]   = ws[OFF_POFF + t];
    }
    int off = poff[N_TYPES - 1] + ((counts[N_TYPES - 1] + BLK - 1) / BLK) * BLK;
    int slot0 = b * EPB;
    if (slot0 >= off) return;                               // whole-block uniform
    int t = 0;
#pragma unroll
    for (int i = 1; i < N_TYPES; ++i)
        if (slot0 >= poff[i]) t = i;
    t = __builtin_amdgcn_readfirstlane(t);                  // block-uniform type
    const int cnt = counts[t];
    const int tbase = poff[t];
    const int* sorted = ws + OFF_SORTED;

    const int tid  = (int)threadIdx.x;
    const int half = __builtin_amdgcn_readfirstlane(tid >> 7);  // wave-uniform
    const int idx  = tid & (EPB - 1);                       // edge 0..127
    const int slot = slot0 + idx;
    const bool valid = (slot - tbase) < cnt;
    // CRASH FIX: clamp to sorted[tbase] (always written for non-empty type),
    // NOT sorted[slot0] (uninitialized when whole block is padding).
    const int e = sorted[valid ? slot : tbase];
    const int node = half ? dsti[e] : srci[e];

    float acc[HID];
#pragma unroll
    for (int j = 0; j < HID; ++j) acc[j] = half ? 0.f : b1[t * HID + j];
    // my half-row of W1[t]: src half rows 0..127, dst half rows 128..255
    const float* Wb = W1 + (size_t)t * (2 * EMB_DIM * HID) + (size_t)half * EMB_DIM * HID;
    const f4* x = (const f4*)(emb + (size_t)node * EMB_DIM);  // 32 f4 = my row

    f4 A[8];
#pragma unroll 1
    for (int c = 0; c < 4; ++c) {                           // 4 rounds (was 8)
#pragma unroll
        for (int k = 0; k < 8; ++k) A[k] = x[c * 8 + k];
        cc32(A, Wb + c * 32 * HID, acc);
    }

    // ---- join: dst half publishes partials, src half reduces + epilogue ----
    if (half) {
#pragma unroll
        for (int j = 0; j < HID; ++j) jbuf[idx][j] = acc[j];
    }
    __syncthreads();
    if (!half && valid) {
        float sc = b2[t];
#pragma unroll
        for (int j = 0; j < HID; ++j) {
            float h = acc[j] + jbuf[idx][j];
            h = (h > 0.f) ? h : 0.01f * h;                  // LeakyReLU(0.01)
            sc = fmaf(h, W2[t * HID + j], sc);
        }
        out[e] = sc;
    }
}

// ---------- ws-too-small fallback: correctness only ----------
__global__ __launch_bounds__(BLK) void fallback_k(
        const float* __restrict__ emb,
        const int* __restrict__ srci, const int* __restrict__ dsti,
        const int* __restrict__ etype,
        const float* __restrict__ W1, const float* __restrict__ b1,
        const float* __restrict__ W2, const float* __restrict__ b2,
        float* __restrict__ out) {
    long long i0 = (long long)blockIdx.x * BLK + threadIdx.x;
    const f4* s4 = (const f4*)emb;
    f4* o4 = (f4*)(out + N_EDGES);
    const long long n4 = (long long)N_NODES * EMB_DIM / 4;
    for (long long i = i0; i < n4; i += (long long)gridDim.x * BLK)
        o4[i] = s4[i];
    for (int e = (int)i0; e < N_EDGES; e += gridDim.x * BLK) {
        int t = etype[e];
        int s = srci[e], d = dsti[e];
        float acc[HID];
#pragma unroll
        for (int j = 0; j < HID; ++j) acc[j] = b1[t * HID + j];
        const float* w = W1 + (size_t)t * 2 * EMB_DIM * HID;
        const f4* x0 = (const f4*)(emb + (size_t)s * EMB_DIM);
        const f4* x1 = (const f4*)(emb + (size_t)d * EMB_DIM);
        f4 A[8];
#pragma unroll 1
        for (int c = 0; c < 8; ++c) {
            const f4* xp = (c < 4) ? x0 : x1;
#pragma unroll
            for (int k = 0; k < 8; ++k) A[k] = xp[(c & 3) * 8 + k];
            cc32(A, w + c * 32 * HID, acc);
        }
        float sc = b2[t];
#pragma unroll
        for (int j = 0; j < HID; ++j) {
            float h = acc[j];
            h = (h > 0.f) ? h : 0.01f * h;
            sc = fmaf(h, W2[t * HID + j], sc);
        }
        out[e] = sc;
    }
}

extern "C" void kernel_launch(void* const* d_in, const int* in_sizes, int n_in,
                              void* d_out, int out_size, void* d_ws, size_t ws_size,
                              hipStream_t stream) {
    const float* emb   = (const float*)d_in[0];
    const int*   eidx  = (const int*)d_in[1];
    const int*   etype = (const int*)d_in[2];
    const float* W1    = (const float*)d_in[3];
    const float* b1    = (const float*)d_in[4];
    const float* W2    = (const float*)d_in[5];
    const float* b2    = (const float*)d_in[6];
    float* out = (float*)d_out;
    const int* srci = eidx;
    const int* dsti = eidx + N_EDGES;

    if (ws_size >= WS_NEED) {
        int* ws = (int*)d_ws;
        hist_k<<<CHUNKS, BLK, 0, stream>>>(etype, ws);
        scatter_k<<<CHUNKS, BLK, 0, stream>>>(etype, ws);
        score_split_k<<<SCORE_BLOCKS + COPY_BLOCKS, BLK, 0, stream>>>(
            emb, srci, dsti, ws, W1, b1, W2, b2, out);
    } else {
        fallback_k<<<2048, BLK, 0, stream>>>(emb, srci, dsti, etype, W1, b1, W2, b2, out);
    }
}